// Round 4
// baseline (416.134 us; speedup 1.0000x reference)
//
#include <hip/hip_runtime.h>

// SSIM loss v4 — v3 row-pair packed-FP32 structure, occupancy-unlocked:
//   - __launch_bounds__(256,6): 6 blocks/CU resident (was 3) to fill the 34%
//     latency-stall fraction seen in R3 counters
//   - wave-uniform y-edge branch: interior blocks prefetch with no row guards
//   - per-block partial sums to d_ws + reducing finalize (drops the memset
//     graph node and the 1536-way atomic tail)
// B=32, C=3, H=W=512 fp32; zero padding (pad=5) matches lax conv semantics.

typedef float v2f __attribute__((ext_vector_type(2)));
typedef float v4f __attribute__((ext_vector_type(4)));

constexpr int IMG    = 512;
constexpr int TPB    = 256;          // threads/block; 1 col/thread
constexpr int SH     = 64;           // output rows per block
constexpr int NPAIR  = 37;           // input row-pairs streamed (74 rows)
constexpr int LW     = 272;          // LDS float4 entries per buffer
constexpr int PLANES = 32 * 3;       // 96
constexpr int NBLK   = (IMG / TPB) * (IMG / SH) * PLANES;  // 1536
constexpr double N_PIX = 25165824.0; // 32*3*512*512

__global__ __launch_bounds__(TPB, 6) void ssim_map_kernel(
    const float* __restrict__ img1, const float* __restrict__ img2,
    double* __restrict__ partial)
{
    constexpr float GW[11] = {
        0.0010283801f, 0.0075987583f, 0.0360007721f, 0.1093607008f,
        0.2130055439f, 0.2660117257f, 0.2130055439f, 0.1093607008f,
        0.0360007721f, 0.0075987583f, 0.0010283801f };
    constexpr float GWp[13] = {      // GWp[k+1] = GW[k], zero-padded ends
        0.0f,
        0.0010283801f, 0.0075987583f, 0.0360007721f, 0.1093607008f,
        0.2130055439f, 0.2660117257f, 0.2130055439f, 0.1093607008f,
        0.0360007721f, 0.0075987583f, 0.0010283801f,
        0.0f };

    __shared__ v4f  sbuf[3][LW];
    __shared__ float wsum[TPB / 64];

    const int tid   = threadIdx.x;
    const int x0    = blockIdx.x * TPB;     // 0 or 256
    const int y0    = blockIdx.y * SH;
    const int plane = blockIdx.z;
    const bool yedge = (blockIdx.y == 0) || (blockIdx.y == (IMG / SH - 1));

    const float* p1 = img1 + (size_t)plane * IMG * IMG;
    const float* p2 = img2 + (size_t)plane * IMG * IMG;

    const int  c    = x0 + tid - 8;
    const bool cok  = (unsigned)c < (unsigned)IMG;
    const int  cc   = cok ? c : 0;                   // clamped (loads masked)
    const int  c2   = x0 + 248 + tid;
    const bool c2ok = (unsigned)c2 < (unsigned)IMG;  // used when tid<16
    const int  cc2  = c2ok ? c2 : 0;

    v2f rg1[6], rg2[6], rg11[6], rg22[6], rg12[6];
    v2f accv = {0.0f, 0.0f};

    float pa1, pb1, pa2, pb2, qa1, qb1, qa2, qb2;

    // guarded prefetch (edge-y blocks): rows may fall outside [0,512)
    auto prefetch_g = [&](int i) {
        const int  rA  = y0 - 5 + 2 * i;
        const int  rB  = rA + 1;
        const bool aok = (unsigned)rA < (unsigned)IMG;   // wave-uniform
        const bool bok = (unsigned)rB < (unsigned)IMG;
        const size_t oA = (size_t)rA * IMG;
        const size_t oB = (size_t)rB * IMG;
        pa1 = (aok && cok) ? p1[oA + cc] : 0.0f;
        pb1 = (bok && cok) ? p1[oB + cc] : 0.0f;
        pa2 = (aok && cok) ? p2[oA + cc] : 0.0f;
        pb2 = (bok && cok) ? p2[oB + cc] : 0.0f;
        if (tid < 16) {
            qa1 = (aok && c2ok) ? p1[oA + cc2] : 0.0f;
            qb1 = (bok && c2ok) ? p1[oB + cc2] : 0.0f;
            qa2 = (aok && c2ok) ? p2[oA + cc2] : 0.0f;
            qb2 = (bok && c2ok) ? p2[oB + cc2] : 0.0f;
        }
    };
    // unguarded prefetch (interior-y blocks): rows always valid
    auto prefetch_f = [&](int i) {
        const size_t oA = (size_t)(y0 - 5 + 2 * i) * IMG;
        const size_t oB = oA + IMG;
        pa1 = cok ? p1[oA + cc] : 0.0f;
        pb1 = cok ? p1[oB + cc] : 0.0f;
        pa2 = cok ? p2[oA + cc] : 0.0f;
        pb2 = cok ? p2[oB + cc] : 0.0f;
        if (tid < 16) {
            qa1 = c2ok ? p1[oA + cc2] : 0.0f;
            qb1 = c2ok ? p1[oB + cc2] : 0.0f;
            qa2 = c2ok ? p2[oA + cc2] : 0.0f;
            qb2 = c2ok ? p2[oB + cc2] : 0.0f;
        }
    };

    if (yedge) prefetch_g(0); else prefetch_f(0);

    for (int ib = 0; ib < NPAIR; ib += 6) {
#pragma unroll
        for (int j = 0; j < 6; ++j) {
            const int i = ib + j;
            if (i < NPAIR) {
                sbuf[j % 3][tid] = v4f{pa1, pb1, pa2, pb2};
                if (tid < 16) sbuf[j % 3][256 + tid] = v4f{qa1, qb1, qa2, qb2};

                if (i + 1 < NPAIR) {
                    if (yedge) prefetch_g(i + 1); else prefetch_f(i + 1);
                }

                __syncthreads();   // RAW on slot j%3; triple buffer kills WAR

                v2f a1 = {0,0}, a2 = {0,0}, a11 = {0,0}, a22 = {0,0}, a12 = {0,0};
                const v4f* sp = &sbuf[j % 3][tid + 3];
#pragma unroll
                for (int k = 0; k < 11; ++k) {
                    const v4f s  = sp[k];
                    const v2f x1 = __builtin_shufflevector(s, s, 0, 1);
                    const v2f x2 = __builtin_shufflevector(s, s, 2, 3);
                    const float g = GW[k];
                    const v2f t1 = g * x1;
                    const v2f t2 = g * x2;
                    a1 += t1;
                    a2 += t2;
                    a11 = __builtin_elementwise_fma(t1, x1, a11);
                    a22 = __builtin_elementwise_fma(t2, x2, a22);
                    a12 = __builtin_elementwise_fma(t1, x2, a12);
                }
                rg1[j] = a1;  rg2[j] = a2;
                rg11[j] = a11; rg22[j] = a22; rg12[j] = a12;
            }

            if (i >= 5 && i < NPAIR) {
                v2f sx1={0,0}, sy1={0,0}, sx2={0,0}, sy2={0,0};
                v2f sx11={0,0}, sy11={0,0}, sx22={0,0}, sy22={0,0};
                v2f sx12={0,0}, sy12={0,0};
#pragma unroll
                for (int m = 0; m < 6; ++m) {
                    const int s = (j + 1 + m) % 6;
                    const v2f wx = { GWp[2*m + 1], GWp[2*m + 2] };
                    const v2f wy = { GWp[2*m],     GWp[2*m + 1] };
                    sx1  = __builtin_elementwise_fma(wx, rg1[s],  sx1);
                    sy1  = __builtin_elementwise_fma(wy, rg1[s],  sy1);
                    sx2  = __builtin_elementwise_fma(wx, rg2[s],  sx2);
                    sy2  = __builtin_elementwise_fma(wy, rg2[s],  sy2);
                    sx11 = __builtin_elementwise_fma(wx, rg11[s], sx11);
                    sy11 = __builtin_elementwise_fma(wy, rg11[s], sy11);
                    sx22 = __builtin_elementwise_fma(wx, rg22[s], sx22);
                    sy22 = __builtin_elementwise_fma(wy, rg22[s], sy22);
                    sx12 = __builtin_elementwise_fma(wx, rg12[s], sx12);
                    sy12 = __builtin_elementwise_fma(wy, rg12[s], sy12);
                }
                const v2f m1  = { sx1.x + sx1.y,  sy1.x + sy1.y };
                const v2f m2  = { sx2.x + sx2.y,  sy2.x + sy2.y };
                const v2f e11 = { sx11.x + sx11.y, sy11.x + sy11.y };
                const v2f e22 = { sx22.x + sx22.y, sy22.x + sy22.y };
                const v2f e12 = { sx12.x + sx12.y, sy12.x + sy12.y };

                const v2f mu11 = m1 * m1;
                const v2f mu22 = m2 * m2;
                const v2f mu12 = m1 * m2;
                const v2f zero = {0.0f, 0.0f};
                const v2f one  = {1.0f, 1.0f};
                const v2f sg1  = __builtin_elementwise_max(e11 - mu11, zero);
                const v2f sg2  = __builtin_elementwise_max(e22 - mu22, zero);
                const v2f sg12 = e12 - mu12;
                const v2f num = (2.0f * mu12 + 1e-4f) * (2.0f * sg12 + 9e-4f);
                const v2f den = (mu11 + mu22 + 1e-4f) * (sg1 + sg2 + 9e-4f);
                v2f v = { num.x * __builtin_amdgcn_rcpf(den.x),
                          num.y * __builtin_amdgcn_rcpf(den.y) };
                v = __builtin_elementwise_min(__builtin_elementwise_max(v, zero), one);
                accv += v;
            }
        }
    }

    float acc = accv.x + accv.y;
#pragma unroll
    for (int off = 32; off > 0; off >>= 1)
        acc += __shfl_down(acc, off, 64);
    if ((tid & 63) == 0) wsum[tid >> 6] = acc;
    __syncthreads();
    if (tid == 0) {
        double blocksum = 0.0;
#pragma unroll
        for (int w = 0; w < TPB / 64; ++w) blocksum += (double)wsum[w];
        const int bid = blockIdx.x + (IMG / TPB) * (blockIdx.y + (IMG / SH) * blockIdx.z);
        partial[bid] = blocksum;   // every slot written: no init needed
    }
}

__global__ __launch_bounds__(256) void ssim_finalize_kernel(
    const double* __restrict__ partial, float* __restrict__ out)
{
    __shared__ double wsum[4];
    const int tid = threadIdx.x;
    double s = 0.0;
#pragma unroll
    for (int k = 0; k < NBLK / 256; ++k) s += partial[tid + 256 * k];
#pragma unroll
    for (int off = 32; off > 0; off >>= 1)
        s += __shfl_down(s, off, 64);
    if ((tid & 63) == 0) wsum[tid >> 6] = s;
    __syncthreads();
    if (tid == 0) {
        double t = wsum[0] + wsum[1] + wsum[2] + wsum[3];
        out[0] = 1.0f - (float)(t / N_PIX);
    }
}

extern "C" void kernel_launch(void* const* d_in, const int* in_sizes, int n_in,
                              void* d_out, int out_size, void* d_ws, size_t ws_size,
                              hipStream_t stream) {
    const float* img1 = (const float*)d_in[0];
    const float* img2 = (const float*)d_in[1];
    float* out = (float*)d_out;
    double* parts = (double*)d_ws;   // 1536 doubles = 12 KB

    dim3 grid(IMG / TPB, IMG / SH, PLANES);          // 2 x 8 x 96 = 1536 blocks
    ssim_map_kernel<<<grid, TPB, 0, stream>>>(img1, img2, parts);
    ssim_finalize_kernel<<<1, 256, 0, stream>>>(parts, out);
}

// Round 5
// 261.384 us; speedup vs baseline: 1.5920x; 1.5920x over previous
//
#include <hip/hip_runtime.h>

// SSIM loss v5 — v3 row-pair packed-FP32 datapath + v4 cleanups, spill fixed:
//   - __launch_bounds__(256,4): VGPR cap 128. R4's (256,6) forced VGPR=40 and
//     spilled the register rings (WRITE_SIZE 48KB->124MB, 2.5x regression).
//     The datapath needs ~64-80 VGPRs; do not request >4 waves/EU.
//   - wave-uniform y-edge branch: interior blocks prefetch with no row guards
//   - per-block partial sums to d_ws + reducing finalize (no memset node)
// B=32, C=3, H=W=512 fp32; zero padding (pad=5) matches lax conv semantics.

typedef float v2f __attribute__((ext_vector_type(2)));
typedef float v4f __attribute__((ext_vector_type(4)));

constexpr int IMG    = 512;
constexpr int TPB    = 256;          // threads/block; 1 col/thread
constexpr int SH     = 64;           // output rows per block
constexpr int NPAIR  = 37;           // input row-pairs streamed (74 rows)
constexpr int LW     = 272;          // LDS float4 entries per buffer
constexpr int PLANES = 32 * 3;       // 96
constexpr int NBLK   = (IMG / TPB) * (IMG / SH) * PLANES;  // 1536
constexpr double N_PIX = 25165824.0; // 32*3*512*512

__global__ __launch_bounds__(TPB, 4) void ssim_map_kernel(
    const float* __restrict__ img1, const float* __restrict__ img2,
    double* __restrict__ partial)
{
    constexpr float GW[11] = {
        0.0010283801f, 0.0075987583f, 0.0360007721f, 0.1093607008f,
        0.2130055439f, 0.2660117257f, 0.2130055439f, 0.1093607008f,
        0.0360007721f, 0.0075987583f, 0.0010283801f };
    constexpr float GWp[13] = {      // GWp[k+1] = GW[k], zero-padded ends
        0.0f,
        0.0010283801f, 0.0075987583f, 0.0360007721f, 0.1093607008f,
        0.2130055439f, 0.2660117257f, 0.2130055439f, 0.1093607008f,
        0.0360007721f, 0.0075987583f, 0.0010283801f,
        0.0f };

    __shared__ v4f  sbuf[3][LW];
    __shared__ float wsum[TPB / 64];

    const int tid   = threadIdx.x;
    const int x0    = blockIdx.x * TPB;     // 0 or 256
    const int y0    = blockIdx.y * SH;
    const int plane = blockIdx.z;
    const bool yedge = (blockIdx.y == 0) || (blockIdx.y == (IMG / SH - 1));

    const float* p1 = img1 + (size_t)plane * IMG * IMG;
    const float* p2 = img2 + (size_t)plane * IMG * IMG;

    const int  c    = x0 + tid - 8;
    const bool cok  = (unsigned)c < (unsigned)IMG;
    const int  cc   = cok ? c : 0;                   // clamped (loads masked)
    const int  c2   = x0 + 248 + tid;
    const bool c2ok = (unsigned)c2 < (unsigned)IMG;  // used when tid<16
    const int  cc2  = c2ok ? c2 : 0;

    v2f rg1[6], rg2[6], rg11[6], rg22[6], rg12[6];
    v2f accv = {0.0f, 0.0f};

    float pa1, pb1, pa2, pb2, qa1, qb1, qa2, qb2;

    // guarded prefetch (edge-y blocks): rows may fall outside [0,512)
    auto prefetch_g = [&](int i) {
        const int  rA  = y0 - 5 + 2 * i;
        const int  rB  = rA + 1;
        const bool aok = (unsigned)rA < (unsigned)IMG;   // wave-uniform
        const bool bok = (unsigned)rB < (unsigned)IMG;
        const size_t oA = (size_t)rA * IMG;
        const size_t oB = (size_t)rB * IMG;
        pa1 = (aok && cok) ? p1[oA + cc] : 0.0f;
        pb1 = (bok && cok) ? p1[oB + cc] : 0.0f;
        pa2 = (aok && cok) ? p2[oA + cc] : 0.0f;
        pb2 = (bok && cok) ? p2[oB + cc] : 0.0f;
        if (tid < 16) {
            qa1 = (aok && c2ok) ? p1[oA + cc2] : 0.0f;
            qb1 = (bok && c2ok) ? p1[oB + cc2] : 0.0f;
            qa2 = (aok && c2ok) ? p2[oA + cc2] : 0.0f;
            qb2 = (bok && c2ok) ? p2[oB + cc2] : 0.0f;
        }
    };
    // unguarded prefetch (interior-y blocks): rows always valid
    auto prefetch_f = [&](int i) {
        const size_t oA = (size_t)(y0 - 5 + 2 * i) * IMG;
        const size_t oB = oA + IMG;
        pa1 = cok ? p1[oA + cc] : 0.0f;
        pb1 = cok ? p1[oB + cc] : 0.0f;
        pa2 = cok ? p2[oA + cc] : 0.0f;
        pb2 = cok ? p2[oB + cc] : 0.0f;
        if (tid < 16) {
            qa1 = c2ok ? p1[oA + cc2] : 0.0f;
            qb1 = c2ok ? p1[oB + cc2] : 0.0f;
            qa2 = c2ok ? p2[oA + cc2] : 0.0f;
            qb2 = c2ok ? p2[oB + cc2] : 0.0f;
        }
    };

    if (yedge) prefetch_g(0); else prefetch_f(0);

    for (int ib = 0; ib < NPAIR; ib += 6) {
#pragma unroll
        for (int j = 0; j < 6; ++j) {
            const int i = ib + j;
            if (i < NPAIR) {
                sbuf[j % 3][tid] = v4f{pa1, pb1, pa2, pb2};
                if (tid < 16) sbuf[j % 3][256 + tid] = v4f{qa1, qb1, qa2, qb2};

                if (i + 1 < NPAIR) {
                    if (yedge) prefetch_g(i + 1); else prefetch_f(i + 1);
                }

                __syncthreads();   // RAW on slot j%3; triple buffer kills WAR

                v2f a1 = {0,0}, a2 = {0,0}, a11 = {0,0}, a22 = {0,0}, a12 = {0,0};
                const v4f* sp = &sbuf[j % 3][tid + 3];
#pragma unroll
                for (int k = 0; k < 11; ++k) {
                    const v4f s  = sp[k];
                    const v2f x1 = __builtin_shufflevector(s, s, 0, 1);
                    const v2f x2 = __builtin_shufflevector(s, s, 2, 3);
                    const float g = GW[k];
                    const v2f t1 = g * x1;
                    const v2f t2 = g * x2;
                    a1 += t1;
                    a2 += t2;
                    a11 = __builtin_elementwise_fma(t1, x1, a11);
                    a22 = __builtin_elementwise_fma(t2, x2, a22);
                    a12 = __builtin_elementwise_fma(t1, x2, a12);
                }
                rg1[j] = a1;  rg2[j] = a2;
                rg11[j] = a11; rg22[j] = a22; rg12[j] = a12;
            }

            if (i >= 5 && i < NPAIR) {
                v2f sx1={0,0}, sy1={0,0}, sx2={0,0}, sy2={0,0};
                v2f sx11={0,0}, sy11={0,0}, sx22={0,0}, sy22={0,0};
                v2f sx12={0,0}, sy12={0,0};
#pragma unroll
                for (int m = 0; m < 6; ++m) {
                    const int s = (j + 1 + m) % 6;
                    const v2f wx = { GWp[2*m + 1], GWp[2*m + 2] };
                    const v2f wy = { GWp[2*m],     GWp[2*m + 1] };
                    sx1  = __builtin_elementwise_fma(wx, rg1[s],  sx1);
                    sy1  = __builtin_elementwise_fma(wy, rg1[s],  sy1);
                    sx2  = __builtin_elementwise_fma(wx, rg2[s],  sx2);
                    sy2  = __builtin_elementwise_fma(wy, rg2[s],  sy2);
                    sx11 = __builtin_elementwise_fma(wx, rg11[s], sx11);
                    sy11 = __builtin_elementwise_fma(wy, rg11[s], sy11);
                    sx22 = __builtin_elementwise_fma(wx, rg22[s], sx22);
                    sy22 = __builtin_elementwise_fma(wy, rg22[s], sy22);
                    sx12 = __builtin_elementwise_fma(wx, rg12[s], sx12);
                    sy12 = __builtin_elementwise_fma(wy, rg12[s], sy12);
                }
                const v2f m1  = { sx1.x + sx1.y,  sy1.x + sy1.y };
                const v2f m2  = { sx2.x + sx2.y,  sy2.x + sy2.y };
                const v2f e11 = { sx11.x + sx11.y, sy11.x + sy11.y };
                const v2f e22 = { sx22.x + sx22.y, sy22.x + sy22.y };
                const v2f e12 = { sx12.x + sx12.y, sy12.x + sy12.y };

                const v2f mu11 = m1 * m1;
                const v2f mu22 = m2 * m2;
                const v2f mu12 = m1 * m2;
                const v2f zero = {0.0f, 0.0f};
                const v2f one  = {1.0f, 1.0f};
                const v2f sg1  = __builtin_elementwise_max(e11 - mu11, zero);
                const v2f sg2  = __builtin_elementwise_max(e22 - mu22, zero);
                const v2f sg12 = e12 - mu12;
                const v2f num = (2.0f * mu12 + 1e-4f) * (2.0f * sg12 + 9e-4f);
                const v2f den = (mu11 + mu22 + 1e-4f) * (sg1 + sg2 + 9e-4f);
                v2f v = { num.x * __builtin_amdgcn_rcpf(den.x),
                          num.y * __builtin_amdgcn_rcpf(den.y) };
                v = __builtin_elementwise_min(__builtin_elementwise_max(v, zero), one);
                accv += v;
            }
        }
    }

    float acc = accv.x + accv.y;
#pragma unroll
    for (int off = 32; off > 0; off >>= 1)
        acc += __shfl_down(acc, off, 64);
    if ((tid & 63) == 0) wsum[tid >> 6] = acc;
    __syncthreads();
    if (tid == 0) {
        double blocksum = 0.0;
#pragma unroll
        for (int w = 0; w < TPB / 64; ++w) blocksum += (double)wsum[w];
        const int bid = blockIdx.x + (IMG / TPB) * (blockIdx.y + (IMG / SH) * blockIdx.z);
        partial[bid] = blocksum;   // every slot written: no init needed
    }
}

__global__ __launch_bounds__(256) void ssim_finalize_kernel(
    const double* __restrict__ partial, float* __restrict__ out)
{
    __shared__ double wsum[4];
    const int tid = threadIdx.x;
    double s = 0.0;
#pragma unroll
    for (int k = 0; k < NBLK / 256; ++k) s += partial[tid + 256 * k];
#pragma unroll
    for (int off = 32; off > 0; off >>= 1)
        s += __shfl_down(s, off, 64);
    if ((tid & 63) == 0) wsum[tid >> 6] = s;
    __syncthreads();
    if (tid == 0) {
        double t = wsum[0] + wsum[1] + wsum[2] + wsum[3];
        out[0] = 1.0f - (float)(t / N_PIX);
    }
}

extern "C" void kernel_launch(void* const* d_in, const int* in_sizes, int n_in,
                              void* d_out, int out_size, void* d_ws, size_t ws_size,
                              hipStream_t stream) {
    const float* img1 = (const float*)d_in[0];
    const float* img2 = (const float*)d_in[1];
    float* out = (float*)d_out;
    double* parts = (double*)d_ws;   // 1536 doubles = 12 KB

    dim3 grid(IMG / TPB, IMG / SH, PLANES);          // 2 x 8 x 96 = 1536 blocks
    ssim_map_kernel<<<grid, TPB, 0, stream>>>(img1, img2, parts);
    ssim_finalize_kernel<<<1, 256, 0, stream>>>(parts, out);
}